// Round 7
// baseline (382.036 us; speedup 1.0000x reference)
//
#include <hip/hip_runtime.h>
#include <hip/hip_bf16.h>

#define DIM  1024
#define RANK 32
#define BATCH 4
#define SEQ  4096
#define MTOT (BATCH * SEQ)   // 16384

typedef short bf16x8 __attribute__((ext_vector_type(8)));          // MFMA A/B frag (8 bf16)
typedef float f32x4 __attribute__((ext_vector_type(4)));           // 16x16 MFMA C/D frag
typedef float f32x16 __attribute__((ext_vector_type(16)));         // 32x32 MFMA C/D frag
typedef unsigned short ushort8v __attribute__((ext_vector_type(8)));
typedef unsigned int uint2v __attribute__((ext_vector_type(2)));

__device__ inline unsigned short f2bf(float f) {
    union { float f; unsigned int u; } v; v.f = f;
    return (unsigned short)((v.u + 0x7FFFu + ((v.u >> 16) & 1u)) >> 16);  // RNE
}

__device__ inline unsigned int pk_bf16(float a, float b) {
    __hip_bfloat162 h = __float22bfloat162_rn(make_float2(a, b));
    unsigned int u; __builtin_memcpy(&u, &h, 4);
    return u;
}

// async global->LDS, 16B per lane; data lands at lds_base + lane*16 (wave-uniform base)
__device__ inline void gl_lds16(const unsigned short* g, unsigned short* l) {
    __builtin_amdgcn_global_load_lds(
        (const __attribute__((address_space(1))) unsigned int*)g,
        (__attribute__((address_space(3))) unsigned int*)l, 16, 0, 0);
}

// ---------------- K0: pack Q*SC, K (fp32 32x1024 each) -> wqk bf16 (64x1024) -----------
__global__ __launch_bounds__(256) void k_cvt_qk(const float* __restrict__ Q,
                                                const float* __restrict__ K,
                                                unsigned short* __restrict__ wqk) {
    int i = blockIdx.x * 256 + threadIdx.x;        // 65536 total
    int row = i >> 10, col = i & 1023;
    const float SC = 0.045084220027779984f;        // 1/(32*ln2)
    float v = (row < RANK) ? Q[row * DIM + col] * SC : K[(row - RANK) * DIM + col];
    wqk[i] = f2bf(v);
}

// ---------------- K1: tiled transpose + fp32->bf16 (VO -> vot[e][d]) -------------------
__global__ __launch_bounds__(256) void k_transpose_cvt(const float* __restrict__ in,
                                                       unsigned short* __restrict__ out,
                                                       int R, int C) {
    __shared__ float tile[64][65];
    const int tid = threadIdx.x;
    const int c0 = blockIdx.x * 64, r0 = blockIdx.y * 64;
    {
        int c = (tid & 15) * 4;
#pragma unroll
        for (int i = 0; i < 4; ++i) {
            int r = (tid >> 4) + i * 16;
            f32x4 v = *(const f32x4*)(in + (size_t)(r0 + r) * C + c0 + c);
            tile[r][c + 0] = v[0]; tile[r][c + 1] = v[1];
            tile[r][c + 2] = v[2]; tile[r][c + 3] = v[3];
        }
    }
    __syncthreads();
    {
        int r = (tid & 15) * 4;
#pragma unroll
        for (int i = 0; i < 4; ++i) {
            int c = (tid >> 4) + i * 16;
            unsigned short o0 = f2bf(tile[r + 0][c]), o1 = f2bf(tile[r + 1][c]);
            unsigned short o2 = f2bf(tile[r + 2][c]), o3 = f2bf(tile[r + 3][c]);
            unsigned short* p = out + (size_t)(c0 + c) * R + r0 + r;
            p[0] = o0; p[1] = o1; p[2] = o2; p[3] = o3;
        }
    }
}

// ---------------- K2: x fp32 -> xbf bf16, row-major passthrough ------------------------
__global__ __launch_bounds__(256) void k_xbf(const float* __restrict__ x,
                                             unsigned short* __restrict__ xbf) {
    size_t i = ((size_t)blockIdx.x * 256 + threadIdx.x) * 8;
    f32x4 v0 = *(const f32x4*)(x + i);
    f32x4 v1 = *(const f32x4*)(x + i + 4);
    ushort8v o;
    o[0] = f2bf(v0[0]); o[1] = f2bf(v0[1]); o[2] = f2bf(v0[2]); o[3] = f2bf(v0[3]);
    o[4] = f2bf(v1[0]); o[5] = f2bf(v1[1]); o[6] = f2bf(v1[2]); o[7] = f2bf(v1[3]);
    *(ushort8v*)(xbf + i) = o;
}

// ---------------- K3: xqk = xbf @ wqk^T  (M=16384, N=64, K=1024), bf16 out -------------
__global__ __launch_bounds__(256) void k_proj(const unsigned short* __restrict__ xbf,
                                              const unsigned short* __restrict__ wqk,
                                              unsigned short* __restrict__ xqk) {
    __shared__ __align__(16) unsigned short a_lds[128 * 32];
    __shared__ __align__(16) unsigned short w_lds[64 * 32];
    const int tid = threadIdx.x;
    const int w = tid >> 6, lane = tid & 63, l15 = lane & 15, quad = lane >> 4;
    const int wm = w & 1, wn = w >> 1;
    const int rowbase = blockIdx.x * 128;

    f32x4 acc[4][2];
#pragma unroll
    for (int mt = 0; mt < 4; ++mt)
#pragma unroll
        for (int nt = 0; nt < 2; ++nt) acc[mt][nt] = (f32x4){0.f, 0.f, 0.f, 0.f};

    const unsigned short* Ab = xbf + (size_t)(rowbase + w * 32 + (lane >> 2)) * DIM + (lane & 3) * 8;
    const unsigned short* Wb = wqk + (size_t)(w * 16 + (lane >> 2)) * DIM + (lane & 3) * 8;

    for (int k0 = 0; k0 < DIM; k0 += 32) {
        gl_lds16(Ab + k0, &a_lds[(w * 32) * 32]);
        gl_lds16(Ab + (size_t)16 * DIM + k0, &a_lds[(w * 32 + 16) * 32]);
        gl_lds16(Wb + k0, &w_lds[(w * 16) * 32]);
        __syncthreads();
        bf16x8 am[4], bn[2];
#pragma unroll
        for (int mt = 0; mt < 4; ++mt)
            am[mt] = *(const bf16x8*)&a_lds[(wm * 64 + mt * 16 + l15) * 32 + quad * 8];
#pragma unroll
        for (int nt = 0; nt < 2; ++nt)
            bn[nt] = *(const bf16x8*)&w_lds[(wn * 32 + nt * 16 + l15) * 32 + quad * 8];
#pragma unroll
        for (int mt = 0; mt < 4; ++mt)
#pragma unroll
            for (int nt = 0; nt < 2; ++nt)
                acc[mt][nt] = __builtin_amdgcn_mfma_f32_16x16x32_bf16(am[mt], bn[nt], acc[mt][nt], 0, 0, 0);
        __syncthreads();
    }
#pragma unroll
    for (int mt = 0; mt < 4; ++mt)
#pragma unroll
        for (int nt = 0; nt < 2; ++nt)
#pragma unroll
            for (int r = 0; r < 4; ++r) {
                int grow = rowbase + wm * 64 + mt * 16 + quad * 4 + r;
                xqk[(size_t)grow * 64 + wn * 32 + nt * 16 + l15] = f2bf(acc[mt][nt][r]);
            }
}

// ---------------- K5 (round-0): xvoT[b][e][u] = (x @ VO)^T. 128e x 256u, BK=64 ---------
// Proven single-buffer 2-barrier structure, 48 KB LDS, 2 blocks/CU.
__global__ __launch_bounds__(512, 4) void k_xvo(const unsigned short* __restrict__ vot,
                                                const unsigned short* __restrict__ xbf,
                                                unsigned short* __restrict__ xvoT) {
    __shared__ __align__(16) unsigned short a_lds[128 * 64];   // 128 e-rows x 128B
    __shared__ __align__(16) unsigned short b_lds[256 * 64];   // 256 u-rows x 128B
    const int tid = threadIdx.x;
    const int w = tid >> 6, lane = tid & 63, l31 = lane & 31, half = lane >> 5;
    const int wm = w & 1, wn = w >> 1;
    const int ubase = blockIdx.x * 256;
    const int ebase = blockIdx.y * 128;
    const int b = blockIdx.z;

    f32x16 acc[2][2];
#pragma unroll
    for (int at = 0; at < 2; ++at)
#pragma unroll
        for (int bt = 0; bt < 2; ++bt)
#pragma unroll
            for (int i = 0; i < 16; ++i) acc[at][bt][i] = 0.f;

    const int sub = lane >> 3;                 // 0..7 rows within a stage call
    const int g = (lane & 7) ^ (sub & 7);      // swizzled global chunk for this lane
    const int Ra = w * 16 + sub;
    const int Rb = w * 32 + sub;
    const unsigned short* Ap = vot + (size_t)(ebase + Ra) * DIM + g * 8;
    const unsigned short* Bp = xbf + (size_t)(b * SEQ + ubase + Rb) * DIM + g * 8;

    for (int k0 = 0; k0 < DIM; k0 += 64) {
#pragma unroll
        for (int c = 0; c < 2; ++c)
            gl_lds16(Ap + (size_t)(c * 8) * DIM + k0, &a_lds[(w * 16 + c * 8) * 64]);
#pragma unroll
        for (int c = 0; c < 4; ++c)
            gl_lds16(Bp + (size_t)(c * 8) * DIM + k0, &b_lds[(w * 32 + c * 8) * 64]);
        __syncthreads();

        const int abase = (wm * 64 + l31) * 64;
        const int bbase = (wn * 64 + l31) * 64;
#pragma unroll
        for (int ks = 0; ks < 4; ++ks) {
            const int soff = ((ks * 2 + half) ^ (l31 & 7)) * 8;
            bf16x8 a0 = *(const bf16x8*)&a_lds[abase + soff];
            bf16x8 a1 = *(const bf16x8*)&a_lds[abase + 2048 + soff];
            bf16x8 b0 = *(const bf16x8*)&b_lds[bbase + soff];
            bf16x8 b1 = *(const bf16x8*)&b_lds[bbase + 2048 + soff];
            acc[0][0] = __builtin_amdgcn_mfma_f32_32x32x16_bf16(a0, b0, acc[0][0], 0, 0, 0);
            acc[0][1] = __builtin_amdgcn_mfma_f32_32x32x16_bf16(a0, b1, acc[0][1], 0, 0, 0);
            acc[1][0] = __builtin_amdgcn_mfma_f32_32x32x16_bf16(a1, b0, acc[1][0], 0, 0, 0);
            acc[1][1] = __builtin_amdgcn_mfma_f32_32x32x16_bf16(a1, b1, acc[1][1], 0, 0, 0);
        }
        __syncthreads();
    }
#pragma unroll
    for (int at = 0; at < 2; ++at)
#pragma unroll
        for (int bt = 0; bt < 2; ++bt)
#pragma unroll
            for (int reg = 0; reg < 16; ++reg) {
                int lr = wm * 64 + at * 32 + (reg & 3) + 8 * (reg >> 2) + 4 * half;
                int u = ubase + wn * 64 + bt * 32 + l31;
                xvoT[(size_t)(b * DIM + ebase + lr) * SEQ + u] = f2bf(acc[at][bt][reg]);
            }
}

// ---------------- K6 v9 (FUSED, producer/consumer): softmax-PV, P never materialized ---
// m114 mechanism: MFMA|VALU overlap comes from DIFFERENT waves at DIFFERENT phases.
// Waves 0-3 (producers): per tile, stage b_lds[(t+1)&1] (8 gl_lds, async all tile),
//   score-MFMA(t+1) (4 MFMA), exp2/pack -> p_lds[(t+1)&1], k(t+2) reg prefetch,
//   own-vmcnt(0)+lgkmcnt(0) drain. Also own the denominator (each producer owns its
//   32 q-rows end-to-end -> writes rden directly, no cross-wave reduce).
// Waves 4-7 (consumers): per tile, 32 PV MFMAs on p_lds[t&1] x b_lds[t&1]; out 128x256
//   split 2q-half x 2e-half per wave (acc 2x4 f32x16 = 128 VGPR).
// ONE barrier per tile; counts identical on both paths (wave-uniform branch).
// Hazards: producers write buf (t+1)&1, consumers read buf t&1 (disjoint); consumer
// reads of (t+1)&1 retired at end of t-1 (lgkmcnt(0)+barrier). LDS 96.5 KB -> 1 blk/CU.
__global__ __launch_bounds__(512, 2) void k_spv(const unsigned short* __restrict__ xqk,
                                                const unsigned short* __restrict__ xvoT,
                                                float* __restrict__ out) {
    __shared__ __align__(16) unsigned short p_lds[2][128 * 64];  // 2 x 16 KB (XOR-swz)
    __shared__ __align__(16) unsigned short b_lds[2][256 * 64];  // 2 x 32 KB
    __shared__ float rden[128];
    const int tid = threadIdx.x;
    const int w = tid >> 6, lane = tid & 63, l31 = lane & 31, half = lane >> 5;

    const int p = blockIdx.x;
    const int xcd = p & 7, t0 = p >> 3;
    const int rowtile = xcd * 16 + (t0 >> 2);   // 0..127
    const int etile = t0 & 3;                   // 0..3
    const int rowbase = rowtile * 128;          // GLOBAL q-row (includes batch)
    const int ebase = etile * 256;
    const int b = rowbase >> 12;

    const int NT = SEQ / 64;                    // 64
    const int sub = lane >> 3;
    const int g8 = (lane & 7) ^ (sub & 7);      // pre-swizzled global chunk

    if (w < 4) {
        // ================= producer =================
        const int pw = w;                       // owns q rows pw*32..+32, both u-halves
        const unsigned short* xqp = xqk + (size_t)(rowbase + pw * 32 + l31) * 64 + half * 8;
        const bf16x8 bq0 = *(const bf16x8*)(xqp);
        const bf16x8 bq1 = *(const bf16x8*)(xqp + 16);
        const unsigned short* xkp = xqk + (size_t)(b * SEQ + l31) * 64 + 32 + half * 8;
        const unsigned short* BpP = xvoT + (size_t)(b * DIM + ebase + pw * 64 + sub) * SEQ + g8 * 8;
        const int pbase = (pw * 32 + l31) * 64 + half * 4;
        float dacc = 0.f;
        bf16x8 kc0[2], kc1[2];

        auto load_k = [&](int tt) {
#pragma unroll
            for (int uu = 0; uu < 2; ++uu) {
                const unsigned short* nx = xkp + (size_t)uu * 2048 + (size_t)tt * 4096;
                kc0[uu] = *(const bf16x8*)(nx);
                kc1[uu] = *(const bf16x8*)(nx + 16);
            }
        };
        auto stage_b = [&](int buf, int tt) {
            unsigned short* bl = b_lds[buf];
#pragma unroll
            for (int c = 0; c < 8; ++c)        // rows pw*64 + c*8 (row&7 = sub invariant)
                gl_lds16(BpP + (size_t)(c * 8) * SEQ + tt * 64, &bl[(pw * 64 + c * 8) * 64]);
        };
        auto score_into = [&](int buf) {
#pragma unroll
            for (int uu = 0; uu < 2; ++uu) {
                f32x16 sc;
#pragma unroll
                for (int i = 0; i < 16; ++i) sc[i] = 0.f;
                sc = __builtin_amdgcn_mfma_f32_32x32x16_bf16(kc0[uu], bq0, sc, 0, 0, 0);
                sc = __builtin_amdgcn_mfma_f32_32x32x16_bf16(kc1[uu], bq1, sc, 0, 0, 0);
#pragma unroll
                for (int g = 0; g < 4; ++g) {
                    float e0 = exp2f(sc[4 * g + 0]), e1 = exp2f(sc[4 * g + 1]);
                    float e2 = exp2f(sc[4 * g + 2]), e3 = exp2f(sc[4 * g + 3]);
                    dacc += (e0 + e1) + (e2 + e3);
                    uint2v dw; dw[0] = pk_bf16(e0, e1); dw[1] = pk_bf16(e2, e3);
                    // chunk uu*4+g at row q -> slot chunk^(q&7); q&7 == l31&7
                    *(uint2v*)&p_lds[buf][pbase + (((uu * 4 + g) ^ (l31 & 7)) * 8)] = dw;
                }
            }
        };

        // prologue: B(0)+p(0) published
        stage_b(0, 0);
        load_k(0);
        score_into(0);
        load_k(1);
        asm volatile("s_waitcnt vmcnt(0) lgkmcnt(0)" ::: "memory");
        __builtin_amdgcn_s_barrier();
        asm volatile("" ::: "memory");

        for (int t = 0; t < NT; ++t) {
            if (t + 1 < NT) {
                stage_b((t + 1) & 1, t + 1);    // async; in flight across score compute
                score_into((t + 1) & 1);        // VALU runs while consumers do PV(t) MFMAs
                load_k((t + 2 < NT) ? (t + 2) : (t + 1));
                asm volatile("s_waitcnt vmcnt(0) lgkmcnt(0)" ::: "memory");
            }
            __builtin_amdgcn_s_barrier();       // end of tile t
            asm volatile("" ::: "memory");
        }

        dacc += __shfl_xor(dacc, 32);           // fold the two u-row halves per q col
        if (half == 0) rden[pw * 32 + l31] = 1.0f / dacc;
        __syncthreads();
        // producers done (no C-write)
    } else {
        // ================= consumer =================
        const int cw = w - 4;
        const int cm = cw & 1, cn = cw >> 1;    // q-half (64), e-half (128)
        f32x16 acc[2][4];
#pragma unroll
        for (int at = 0; at < 2; ++at)
#pragma unroll
            for (int bt = 0; bt < 4; ++bt)
#pragma unroll
                for (int i = 0; i < 16; ++i) acc[at][bt][i] = 0.f;

        __builtin_amdgcn_s_barrier();           // match producer prologue barrier
        asm volatile("" ::: "memory");

        const int abase = (cm * 64 + l31) * 64;
        const int bbase = (cn * 128 + l31) * 64;
        for (int t = 0; t < NT; ++t) {
            const unsigned short* pl = p_lds[t & 1];
            const unsigned short* bl = b_lds[t & 1];
            __builtin_amdgcn_s_setprio(1);
#pragma unroll
            for (int ks = 0; ks < 4; ++ks) {
                const int soff = ((ks * 2 + half) ^ (l31 & 7)) * 8;
                bf16x8 a0 = *(const bf16x8*)&pl[abase + soff];
                bf16x8 a1 = *(const bf16x8*)&pl[abase + 2048 + soff];
                bf16x8 b0 = *(const bf16x8*)&bl[bbase + soff];
                bf16x8 b1 = *(const bf16x8*)&bl[bbase + 2048 + soff];
                bf16x8 b2 = *(const bf16x8*)&bl[bbase + 4096 + soff];
                bf16x8 b3 = *(const bf16x8*)&bl[bbase + 6144 + soff];
                acc[0][0] = __builtin_amdgcn_mfma_f32_32x32x16_bf16(a0, b0, acc[0][0], 0, 0, 0);
                acc[0][1] = __builtin_amdgcn_mfma_f32_32x32x16_bf16(a0, b1, acc[0][1], 0, 0, 0);
                acc[0][2] = __builtin_amdgcn_mfma_f32_32x32x16_bf16(a0, b2, acc[0][2], 0, 0, 0);
                acc[0][3] = __builtin_amdgcn_mfma_f32_32x32x16_bf16(a0, b3, acc[0][3], 0, 0, 0);
                acc[1][0] = __builtin_amdgcn_mfma_f32_32x32x16_bf16(a1, b0, acc[1][0], 0, 0, 0);
                acc[1][1] = __builtin_amdgcn_mfma_f32_32x32x16_bf16(a1, b1, acc[1][1], 0, 0, 0);
                acc[1][2] = __builtin_amdgcn_mfma_f32_32x32x16_bf16(a1, b2, acc[1][2], 0, 0, 0);
                acc[1][3] = __builtin_amdgcn_mfma_f32_32x32x16_bf16(a1, b3, acc[1][3], 0, 0, 0);
            }
            __builtin_amdgcn_s_setprio(0);
            asm volatile("s_waitcnt lgkmcnt(0)" ::: "memory");   // my ds_reads retired
            __builtin_amdgcn_s_barrier();       // end of tile t
            asm volatile("" ::: "memory");
        }
        __syncthreads();                        // rden published by producers

#pragma unroll
        for (int at = 0; at < 2; ++at)
#pragma unroll
            for (int bt = 0; bt < 4; ++bt)
#pragma unroll
                for (int reg = 0; reg < 16; ++reg) {
                    int lr = cm * 64 + at * 32 + (reg & 3) + 8 * (reg >> 2) + 4 * half;
                    int e = ebase + cn * 128 + bt * 32 + l31;
                    out[(size_t)(rowbase + lr) * DIM + e] = acc[at][bt][reg] * rden[lr];
                }
    }
}

extern "C" void kernel_launch(void* const* d_in, const int* in_sizes, int n_in,
                              void* d_out, int out_size, void* d_ws, size_t ws_size,
                              hipStream_t stream) {
    const float* x  = (const float*)d_in[0];
    const float* Q  = (const float*)d_in[1];
    const float* K  = (const float*)d_in[2];
    const float* VO = (const float*)d_in[3];
    float* out = (float*)d_out;

    char* ws = (char*)d_ws;
    unsigned short* wqk  = (unsigned short*)(ws + 0);           // 64x1024 bf16        128 KB
    unsigned short* vot  = (unsigned short*)(ws + 131072);      // 1024x1024 bf16        2 MB
    unsigned short* xqk  = (unsigned short*)(ws + 2228224);     // 16384x64 bf16         2 MB
    unsigned short* xbf  = (unsigned short*)(ws + 4325376);     // 16384x1024 bf16      32 MB
    unsigned short* xvoT = (unsigned short*)(ws + 37879808);    // 4x1024x4096 bf16     32 MB

    k_cvt_qk<<<256, 256, 0, stream>>>(Q, K, wqk);
    k_transpose_cvt<<<dim3(16, 16, 1), 256, 0, stream>>>(VO, vot, 1024, 1024);
    k_xbf<<<8192, 256, 0, stream>>>(x, xbf);
    k_proj<<<128, 256, 0, stream>>>(xbf, wqk, xqk);
    k_xvo<<<dim3(16, 8, BATCH), 512, 0, stream>>>(vot, xbf, xvoT);
    k_spv<<<dim3(512, 1, 1), 512, 0, stream>>>(xqk, xvoT, out);
}